// Round 5
// baseline (298.717 us; speedup 1.0000x reference)
//
#include <hip/hip_runtime.h>
#include <math.h>

// ---------------------------------------------------------------------------
// ConvCaps fused pipeline, MFMA bf16 v2.
// R5 changes vs R4 (theory: occupancy/latency, MfmaUtil 17.5% -> ~30%):
//   * gemm_fused/gemm_act: BM 128->64, 128-thread 2-wave blocks
//     (grid 576->1152 / 384->768=3 per CU exactly) — more waves/CU, less tail.
//   * B-fragment register double-buffering: prefetch chunk ch+1's B frags
//     before MFMA of chunk ch — no fresh global-load latency after barriers.
// Math/layouts identical to R4 (passed, absmax 0.0156).
// ---------------------------------------------------------------------------

typedef unsigned short u16;
typedef __attribute__((ext_vector_type(8))) short short8;
typedef __attribute__((ext_vector_type(16))) float f32x16;

#define MFMA32(a, b, c) __builtin_amdgcn_mfma_f32_32x32x16_bf16(a, b, c, 0, 0, 0)

#define LN_EPS 1e-8f

// f32 region offsets (float index)
#define O_MU    0
#define O_RSTD  256
#define O_W2    512
#define O_BN1S  1536
#define O_BN1B  1824
#define O_BN2S  2112
#define O_BN2B  2656
#define O_ZB    3200     // 64 zero floats (OOB staging target)

// byte offsets of big regions
#define O_G_B     16384ull                       // u16[16777216]  (33.5 MB)
#define O_AACT_B  (O_G_B + 33554432ull)          // u16[8192*320]  (5.24 MB)
#define O_PART_B  (O_AACT_B + 5242880ull)        // f32[8192*544]  (17.8 MB)
#define O_WF_B    (O_PART_B + 17825792ull)       // u16[9*72*6144] (7.96 MB)
#define O_WA_B    (O_WF_B + 7962624ull)          // u16[6*5*6144]  (0.37 MB)

__device__ __forceinline__ u16 f2bf(float f) {
  union { float f; unsigned u; } v; v.f = f;
  unsigned r = (v.u + 0x7fffu + ((v.u >> 16) & 1u)) >> 16;
  return (u16)r;
}

__device__ __forceinline__ void gll16(const void* g, void* l) {
  __builtin_amdgcn_global_load_lds(
      (const __attribute__((address_space(1))) unsigned int*)g,
      (__attribute__((address_space(3))) unsigned int*)l, 16, 0, 0);
}

// ---------------------------------------------------------------------------
__global__ __launch_bounds__(256) void prep_kernel(
    const float* __restrict__ wts, const float* __restrict__ gamma,
    const float* __restrict__ bn1s, const float* __restrict__ bn1bi,
    const float* __restrict__ bn1m, const float* __restrict__ bn1v,
    const float* __restrict__ bn2s, const float* __restrict__ bn2bi,
    const float* __restrict__ bn2m, const float* __restrict__ bn2v,
    float* __restrict__ ws)
{
  __shared__ float wsm[32 * 33];
  __shared__ float gs[32];
  int t = threadIdx.x;
  if (t < 33) {
    float mx = -1e30f;
    for (int c = 0; c < 32; ++c) mx = fmaxf(mx, wts[c * 33 + t]);
    float sum = 0.f;
    for (int c = 0; c < 32; ++c) {
      float e = expf(wts[c * 33 + t] - mx);
      wsm[c * 33 + t] = e; sum += e;
    }
    float inv = 1.f / sum;
    for (int c = 0; c < 32; ++c) wsm[c * 33 + t] *= inv;
  }
  if (t == 64) {
    float mx = -1e30f;
    for (int d = 0; d < 32; ++d) mx = fmaxf(mx, gamma[d]);
    float sum = 0.f;
    for (int d = 0; d < 32; ++d) { float e = expf(gamma[d] - mx); gs[d] = e; sum += e; }
    float inv = 1.f / sum;
    for (int d = 0; d < 32; ++d) gs[d] *= inv;
  }
  __syncthreads();
  for (int i = t; i < 1024; i += 256) {
    int c = i >> 5, d = i & 31;
    ws[O_W2 + i] = (wsm[c * 33 + d] + wsm[c * 33 + 32] * gs[d]) * gamma[d];
  }
  for (int i = t; i < 288; i += 256) {
    float s = bn1s[i] / sqrtf(bn1v[i] + 1e-5f);
    ws[O_BN1S + i] = s;
    ws[O_BN1B + i] = bn1bi[i] - bn1m[i] * s;
  }
  for (int i = t; i < 544; i += 256) {
    float s = bn2s[i] / sqrtf(bn2v[i] + 1e-5f);
    ws[O_BN2S + i] = s;
    ws[O_BN2B + i] = bn2bi[i] - bn2m[i] * s;
  }
  if (t < 64) ws[O_ZB + t] = 0.f;
}

// ---------------------------------------------------------------------------
__global__ __launch_bounds__(256) void stats_kernel(
    const float* __restrict__ x, float* __restrict__ ws, u16* __restrict__ Aact)
{
  int g = blockIdx.x;
  int b = g >> 5, cb = g & 31;
  const float* base = x + (((size_t)(b * 544 + cb * 16)) << 12);
  float s = 0.f, q = 0.f;
  for (int idx = threadIdx.x; idx < 65536; idx += 256) {
    int p = idx & 4095;
    int hi = p >> 6, wi = p & 63;
    float wh = ((hi & 1) && hi != 63) ? 2.f : 1.f;
    float ww = ((wi & 1) && wi != 63) ? 2.f : 1.f;
    float v = base[idx];
    float wgt = wh * ww;
    s += wgt * v;
    q += wgt * v * v;
  }
  __shared__ float sb[256], qb[256];
  int t = threadIdx.x;
  sb[t] = s; qb[t] = q;
  __syncthreads();
  for (int off = 128; off > 0; off >>= 1) {
    if (t < off) { sb[t] += sb[t + off]; qb[t] += qb[t + off]; }
    __syncthreads();
  }
  if (t == 0) {
    const float N = 147456.f;
    float mean = sb[0] / N;
    float var = (qb[0] - sb[0] * sb[0] / N) / (N - 1.f);
    ws[O_MU + g] = mean;
    ws[O_RSTD + g] = 1.f / sqrtf(var + LN_EPS);
  }
  for (int i = t; i < 1024; i += 256) {
    int pos = (g << 5) + (i >> 5);
    Aact[(size_t)pos * 320 + 288 + (i & 31)] = 0;
  }
}

// ---------------------------------------------------------------------------
// Weight conversion to fragment-linear bf16.
// Wf slot layout: [ob(9)][ch(72)][nt(3)][ks(4)][lane(64)][8 elems]
// Wa slot layout: [ob(6)][ch(5)][nt(3)][ks(4)][lane(64)][8 elems]
__global__ __launch_bounds__(256) void wcvt_kernel(
    const float* __restrict__ w1, const float* __restrict__ w2,
    u16* __restrict__ Wf, u16* __restrict__ Wa)
{
  int sid = blockIdx.x * 256 + threadIdx.x;   // < 520704 exactly
  if (sid < 497664) {
    int cb = sid / 768, si = sid - cb * 768;
    int ob = cb / 72, ch = cb - ob * 72;
    int nt = si >> 8, ks = (si >> 6) & 3, l2 = si & 63;
    int o = ob * 96 + (nt << 5) + (l2 & 31);
    int kf = (ch << 6) + (ks << 4) + ((l2 >> 5) << 3);
    u16* dst = Wf + (size_t)sid * 8;
#pragma unroll
    for (int e = 0; e < 8; ++e) {
      int k = kf + e;
      float v = 0.f;
      if (o < 288) v = w1[(size_t)o * 4608 + k];
      else if (o < 832) v = w2[(size_t)(o - 288) * 4896 + k];
      dst[e] = f2bf(v);
    }
  } else {
    int s2 = sid - 497664;                    // < 23040
    int cb = s2 / 768, si = s2 - cb * 768;
    int ob = cb / 5, ch = cb - ob * 5;
    int nt = si >> 8, ks = (si >> 6) & 3, l2 = si & 63;
    int o = ob * 96 + (nt << 5) + (l2 & 31);
    int kf = (ch << 6) + (ks << 4) + ((l2 >> 5) << 3);
    u16* dst = Wa + (size_t)s2 * 8;
#pragma unroll
    for (int e = 0; e < 8; ++e) {
      int k = kf + e;
      float v = (o < 544 && k < 288) ? w2[(size_t)o * 4896 + 4608 + k] : 0.f;
      dst[e] = f2bf(v);
    }
  }
}

// ---------------------------------------------------------------------------
__global__ __launch_bounds__(256) void g_kernel(
    const float* __restrict__ x, const float* __restrict__ ws,
    u16* __restrict__ Gb)
{
  __shared__ __align__(16) float raw[16][545];
  __shared__ __align__(16) float ut[16][576];
  __shared__ float w2s[1024];
  __shared__ float mus[32], rss[32];
  int t = threadIdx.x;
  int pb = blockIdx.x;
  int b = pb >> 8, hi = (pb >> 2) & 63, wi0 = (pb & 3) << 4;

  {
    int ch0 = t >> 4, wl = t & 15;
    size_t gbase = ((size_t)b * 544) << 12;
    size_t rowoff = ((size_t)hi << 6) + (size_t)(wi0 + wl);
    for (int it = 0; it < 34; ++it) {
      int ch = it * 16 + ch0;
      raw[wl][ch] = x[gbase + ((size_t)ch << 12) + rowoff];
    }
  }
  for (int i = t; i < 1024; i += 256) w2s[i] = ws[O_W2 + i];
  if (t < 32) { mus[t] = ws[O_MU + b * 32 + t]; rss[t] = ws[O_RSTD + b * 32 + t]; }
  __syncthreads();

  {
    int dl = t & 15, psp = t >> 4;
    for (int it = 0; it < 32; ++it) {
      int pix = it >> 1, half = it & 1;
      int dp = half * 16 + dl;
      int j = (dp << 4) + psp;
      int cbv = j & 31, psv = j >> 5;
      float val = (raw[pix][(cbv << 4) + psv] - mus[cbv]) * rss[cbv];
      ut[pix][psp * 36 + dp] = raw[pix][512 + dp] * val;
    }
  }
  __syncthreads();

  {
    int c0 = t >> 4, psp = t & 15;
    float w2a[32], w2b[32];
#pragma unroll
    for (int d = 0; d < 32; ++d) {
      w2a[d] = w2s[c0 * 32 + d];
      w2b[d] = w2s[(c0 + 16) * 32 + d];
    }
    u16* Gp = Gb + ((size_t)((((b << 6) + hi) << 6) + wi0)) * 512;
    for (int pix = 0; pix < 16; ++pix) {
      float acc0 = 0.f, acc1 = 0.f;
      const float* up = &ut[pix][psp * 36];
#pragma unroll
      for (int k = 0; k < 8; ++k) {
        float4 u4 = *reinterpret_cast<const float4*>(up + 4 * k);
        acc0 = fmaf(w2a[4 * k + 0], u4.x, acc0);
        acc0 = fmaf(w2a[4 * k + 1], u4.y, acc0);
        acc0 = fmaf(w2a[4 * k + 2], u4.z, acc0);
        acc0 = fmaf(w2a[4 * k + 3], u4.w, acc0);
        acc1 = fmaf(w2b[4 * k + 0], u4.x, acc1);
        acc1 = fmaf(w2b[4 * k + 1], u4.y, acc1);
        acc1 = fmaf(w2b[4 * k + 2], u4.z, acc1);
        acc1 = fmaf(w2b[4 * k + 3], u4.w, acc1);
      }
      u16* gp = Gp + (size_t)pix * 512;
      gp[t] = f2bf(acc0);
      gp[256 + t] = f2bf(acc1);
    }
  }
}

// ---------------------------------------------------------------------------
// Fused GEMM: M=8192, N=864 (288 conv1 + 544 conv2-G + 32 pad), K=4608.
// BM=64, BN=96, 2 waves (128 thr), wave tile 32x96, mfma 32x32x16.
// Grid 1152 = 8 xcd * 9 ob * 16 mloc; mt = xcd + mloc*8 (0..127).
__global__ __launch_bounds__(128) void gemm_fused(
    const u16* __restrict__ Gb, const u16* __restrict__ Wf,
    const float* __restrict__ wsf, u16* __restrict__ Aact,
    float* __restrict__ partial)
{
  __shared__ __align__(16) u16 Al[2][64 * 64];   // 16 KB
  const int t = threadIdx.x;
  const int wid = t >> 6, l = t & 63;
  int bx = blockIdx.x;
  int xcd = bx & 7, idx = bx >> 3;          // idx < 144
  int ob = idx >> 4;                        // 0..8
  int mt = xcd + ((idx & 15) << 3);         // 0..127
  int p0 = mt << 6;

  // staging per-lane precompute (4 issues of 8 rows per wave; rows 0..63)
  int hb[4], wb[4], jsw[4], srow[4];
  size_t pbs[4];
#pragma unroll
  for (int s = 0; s < 4; ++s) {
    int r = (wid << 5) + (s << 3) + (l >> 3);
    int pos = p0 + r;
    int b_ = pos >> 10, h_ = (pos >> 5) & 31, w_ = pos & 31;
    pbs[s] = ((size_t)b_) << 12;
    hb[s] = 2 * h_ - 1;
    wb[s] = 2 * w_ - 1;
    jsw[s] = ((l & 7) ^ (r & 7)) << 3;
    srow[s] = (wid << 5) + (s << 3);
  }
  const u16* zb = (const u16*)(wsf + O_ZB);
  const size_t wrow = (size_t)(ob * 72) * 6144 + (l << 3);

  f32x16 acc0 = {}, acc1 = {}, acc2 = {};

  auto stage = [&](int ch, int buf) {
    int kpos = ch >> 3;
    int kh = kpos / 3, kw = kpos - kh * 3;
    int c0 = (ch & 7) << 6;
#pragma unroll
    for (int s = 0; s < 4; ++s) {
      int hi = hb[s] + kh, wi = wb[s] + kw;
      bool ok = ((unsigned)hi < 64u) && ((unsigned)wi < 64u);
      const u16* src = ok
          ? (Gb + ((pbs[s] + ((size_t)hi << 6) + (size_t)wi) << 9) + c0 + jsw[s])
          : (zb + jsw[s]);
      gll16(src, &Al[buf][srow[s] << 6]);
    }
  };
  auto loadB = [&](int ch, short8* bf) {
    const u16* wbase = Wf + wrow + (size_t)ch * 6144;
#pragma unroll
    for (int k2 = 0; k2 < 12; ++k2)
      bf[k2] = *(const short8*)(wbase + (k2 << 9));
  };
  const int rr = (wid << 5) + (l & 31);
  auto mfmaPhase = [&](const short8* bf, int buf) {
#pragma unroll
    for (int ks = 0; ks < 4; ++ks) {
      int jl = (ks << 1) + (l >> 5);
      short8 av = *(const short8*)&Al[buf][(rr << 6) + ((jl ^ (rr & 7)) << 3)];
      acc0 = MFMA32(av, bf[ks], acc0);
      acc1 = MFMA32(av, bf[4 + ks], acc1);
      acc2 = MFMA32(av, bf[8 + ks], acc2);
    }
  };

  short8 bfa[12], bfb[12];
  loadB(0, bfa);
  stage(0, 0);
  __syncthreads();

  for (int ch = 0; ch < 72; ch += 2) {
    loadB(ch + 1, bfb);
    stage(ch + 1, 1);
    mfmaPhase(bfa, 0);
    __syncthreads();
    if (ch + 2 < 72) { loadB(ch + 2, bfa); stage(ch + 2, 0); }
    mfmaPhase(bfb, 1);
    __syncthreads();
  }

  // epilogue
  if (ob < 3) {
    const float* s1 = wsf + O_BN1S;
    const float* b1 = wsf + O_BN1B;
#pragma unroll
    for (int nt = 0; nt < 3; ++nt) {
      int o = ob * 96 + (nt << 5) + (l & 31);
      float sc = s1[o], bi = b1[o];
      f32x16 a = (nt == 0) ? acc0 : ((nt == 1) ? acc1 : acc2);
#pragma unroll
      for (int reg = 0; reg < 16; ++reg) {
        int rowD = (reg & 3) + ((reg >> 2) << 3) + ((l >> 5) << 2);
        int pos = p0 + (wid << 5) + rowD;
        float z = a[reg] * sc + bi;
        float sg = 1.f / (1.f + expf(-z));
        Aact[(size_t)pos * 320 + o] = f2bf(sg);
      }
    }
  } else {
#pragma unroll
    for (int nt = 0; nt < 3; ++nt) {
      int o2 = ob * 96 - 288 + (nt << 5) + (l & 31);
      f32x16 a = (nt == 0) ? acc0 : ((nt == 1) ? acc1 : acc2);
      if (o2 < 544) {
#pragma unroll
        for (int reg = 0; reg < 16; ++reg) {
          int rowD = (reg & 3) + ((reg >> 2) << 3) + ((l >> 5) << 2);
          int pos = p0 + (wid << 5) + rowD;
          partial[(size_t)pos * 544 + o2] = a[reg];
        }
      }
    }
  }
}

// ---------------------------------------------------------------------------
// Act GEMM: M=8192, N=576 (544+32 pad), K=320. + partial, BN2, relu -> NCHW.
// BM=64, 2 waves (128 thr). Grid 768 = 8 xcd * 6 ob * 16 mloc (3 blocks/CU).
__global__ __launch_bounds__(128) void gemm_act(
    const u16* __restrict__ Aact, const u16* __restrict__ Wa,
    const float* __restrict__ partial, const float* __restrict__ wsf,
    float* __restrict__ outp)
{
  __shared__ __align__(16) char lraw[96 * 65 * 4];    // 24960 B
  u16 (*Al)[64 * 64] = (u16 (*)[64 * 64])lraw;        // staging: first 16 KB
  float* T = (float*)lraw;                            // epilogue transpose
  const int t = threadIdx.x;
  const int wid = t >> 6, l = t & 63;
  int bx = blockIdx.x;
  int xcd = bx & 7, idx = bx >> 3;          // idx < 96
  int ob = idx >> 4;                        // 0..5
  int mt = xcd + ((idx & 15) << 3);         // 0..127
  int p0 = mt << 6;

  const u16* abase[4];
  int srow[4];
#pragma unroll
  for (int s = 0; s < 4; ++s) {
    int r = (wid << 5) + (s << 3) + (l >> 3);
    int jsw = ((l & 7) ^ (r & 7)) << 3;
    srow[s] = (wid << 5) + (s << 3);
    abase[s] = Aact + (size_t)(p0 + r) * 320 + jsw;
  }
  const size_t wrow = (size_t)(ob * 5) * 6144 + (l << 3);

  f32x16 acc0 = {}, acc1 = {}, acc2 = {};

  auto stage = [&](int ch, int buf) {
#pragma unroll
    for (int s = 0; s < 4; ++s)
      gll16(abase[s] + (ch << 6), &Al[buf][srow[s] << 6]);
  };
  auto loadB = [&](int ch, short8* bf) {
    const u16* wbase = Wa + wrow + (size_t)ch * 6144;
#pragma unroll
    for (int k2 = 0; k2 < 12; ++k2)
      bf[k2] = *(const short8*)(wbase + (k2 << 9));
  };
  const int rr = (wid << 5) + (l & 31);
  auto mfmaPhase = [&](const short8* bf, int buf) {
#pragma unroll
    for (int ks = 0; ks < 4; ++ks) {
      int jl = (ks << 1) + (l >> 5);
      short8 av = *(const short8*)&Al[buf][(rr << 6) + ((jl ^ (rr & 7)) << 3)];
      acc0 = MFMA32(av, bf[ks], acc0);
      acc1 = MFMA32(av, bf[4 + ks], acc1);
      acc2 = MFMA32(av, bf[8 + ks], acc2);
    }
  };

  short8 bfa[12], bfb[12];
  loadB(0, bfa);
  stage(0, 0);
  __syncthreads();

  for (int ch = 0; ch < 5; ch += 2) {
    if (ch + 1 < 5) { loadB(ch + 1, bfb); stage(ch + 1, 1); }
    mfmaPhase(bfa, 0);
    __syncthreads();
    if (ch + 1 < 5) {
      if (ch + 2 < 5) { loadB(ch + 2, bfa); stage(ch + 2, 0); }
      mfmaPhase(bfb, 1);
      __syncthreads();
    }
  }
  __syncthreads();   // protect T-union overwrite of Al

  // epilogue: +partial, BN2, relu -> LDS transpose -> coalesced NCHW store
  const float* s2p = wsf + O_BN2S;
  const float* b2p = wsf + O_BN2B;
#pragma unroll
  for (int nt = 0; nt < 3; ++nt) {
    int ol = (nt << 5) + (l & 31);
    int o = ob * 96 + ol;
    float sc = 0.f, bi = 0.f;
    if (o < 544) { sc = s2p[o]; bi = b2p[o]; }
    f32x16 a = (nt == 0) ? acc0 : ((nt == 1) ? acc1 : acc2);
#pragma unroll
    for (int reg = 0; reg < 16; ++reg) {
      int rowD = (reg & 3) + ((reg >> 2) << 3) + ((l >> 5) << 2);
      int pos = p0 + (wid << 5) + rowD;
      float pz = 0.f;
      if (o < 544) pz = partial[(size_t)pos * 544 + o];
      float z = (a[reg] + pz) * sc + bi;
      T[ol * 65 + (wid << 5) + rowD] = fmaxf(z, 0.f);
    }
  }
  __syncthreads();
  for (int s2 = t; s2 < 1536; s2 += 128) {
    int ol = s2 >> 4, c4 = s2 & 15;
    int o = ob * 96 + ol;
    if (o < 544) {
      int pos0 = p0 + (c4 << 2);
      int b_ = pos0 >> 10, hw0 = pos0 & 1023;
      int base = ol * 65 + (c4 << 2);
      float4 v;
      v.x = T[base]; v.y = T[base + 1]; v.z = T[base + 2]; v.w = T[base + 3];
      *(float4*)&outp[(((size_t)(b_ * 544 + o)) << 10) + hw0] = v;
    }
  }
}

// ---------------------------------------------------------------------------
extern "C" void kernel_launch(void* const* d_in, const int* in_sizes, int n_in,
                              void* d_out, int out_size, void* d_ws,
                              size_t ws_size, hipStream_t stream)
{
  const float* x       = (const float*)d_in[0];
  const float* wts     = (const float*)d_in[1];
  const float* gamma   = (const float*)d_in[2];
  const float* conv1_w = (const float*)d_in[3];
  const float* bn1s    = (const float*)d_in[4];
  const float* bn1b    = (const float*)d_in[5];
  const float* bn1m    = (const float*)d_in[6];
  const float* bn1v    = (const float*)d_in[7];
  const float* conv2_w = (const float*)d_in[8];
  const float* bn2s    = (const float*)d_in[9];
  const float* bn2b    = (const float*)d_in[10];
  const float* bn2m    = (const float*)d_in[11];
  const float* bn2v    = (const float*)d_in[12];

  char* wsb = (char*)d_ws;
  float* wsf = (float*)d_ws;
  u16* Gb    = (u16*)(wsb + O_G_B);
  u16* Aact  = (u16*)(wsb + O_AACT_B);
  float* prt = (float*)(wsb + O_PART_B);
  u16* Wf    = (u16*)(wsb + O_WF_B);
  u16* Wa    = (u16*)(wsb + O_WA_B);
  float* out = (float*)d_out;

  prep_kernel<<<1, 256, 0, stream>>>(wts, gamma, bn1s, bn1b, bn1m, bn1v,
                                     bn2s, bn2b, bn2m, bn2v, wsf);
  stats_kernel<<<256, 256, 0, stream>>>(x, wsf, Aact);
  wcvt_kernel<<<2034, 256, 0, stream>>>(conv1_w, conv2_w, Wf, Wa);
  g_kernel<<<2048, 256, 0, stream>>>(x, wsf, Gb);
  gemm_fused<<<1152, 128, 0, stream>>>(Gb, Wf, wsf, Aact, prt);
  gemm_act<<<768, 128, 0, stream>>>(Aact, Wa, prt, wsf, out);
}